// Round 2
// baseline (71.363 us; speedup 1.0000x reference)
//
#include <hip/hip_runtime.h>

// C[b,g] = softor_s( softand_l( x[b, I[g,s,l]] ) ), gamma=1e-3.
// softand~min, softor~max; composed error <= gamma*ln32 = 3.5e-3 << 1.71e-2
// threshold -> compute hard max-of-min.
//
// Layout trick: B=64 == wave width. Transpose x to xT[g][b]; then for each
// wave-uniform index j, the wave reads xT[j*64+lane] as ONE coalesced 256 B
// L2 load. No LDS gather (no bank conflicts), no cross-lane reduction at all:
// min over l and max over s are per-lane register ops.

#define B_DIM 64
#define G_DIM 2048
#define S_DIM 32
#define L_DIM 8

// x[64][2048] -> xT[2048][64]
__global__ __launch_bounds__(256) void transpose_kernel(
    const float* __restrict__ x, float* __restrict__ xT) {
  __shared__ float t[64][65];
  const int g0 = blockIdx.x * 64;
  const int tg = threadIdx.x & 63;   // g within tile
  const int tb = threadIdx.x >> 6;   // 0..3
#pragma unroll
  for (int r = 0; r < 16; ++r) {
    const int b = tb + r * 4;
    t[tg][b] = x[b * G_DIM + g0 + tg];     // coalesced read, stride-65 LDS write
  }
  __syncthreads();
#pragma unroll
  for (int r = 0; r < 16; ++r) {
    const int g = tb + r * 4;
    xT[(g0 + g) * B_DIM + tg] = t[g][tg];  // coalesced 256 B write per row
  }
}

__global__ __launch_bounds__(256) void gather_minmax_kernel(
    const float* __restrict__ xT, const int* __restrict__ idx,
    float* __restrict__ out) {
  const int lane = threadIdx.x & 63;  // = b
  // One wave per g; force wave-uniformity so idx loads can scalarize.
  const int g =
      __builtin_amdgcn_readfirstlane(blockIdx.x * 4 + (threadIdx.x >> 6));
  const int* ip = idx + g * (S_DIM * L_DIM);

  float acc = -1e30f;
#pragma unroll 4
  for (int s = 0; s < S_DIM; ++s) {
    const int4 i0 = ((const int4*)(ip + s * 8))[0];
    const int4 i1 = ((const int4*)(ip + s * 8))[1];
    const float v0 = xT[i0.x * B_DIM + lane];
    const float v1 = xT[i0.y * B_DIM + lane];
    const float v2 = xT[i0.z * B_DIM + lane];
    const float v3 = xT[i0.w * B_DIM + lane];
    const float v4 = xT[i1.x * B_DIM + lane];
    const float v5 = xT[i1.y * B_DIM + lane];
    const float v6 = xT[i1.z * B_DIM + lane];
    const float v7 = xT[i1.w * B_DIM + lane];
    const float m = fminf(fminf(fminf(v0, v1), fminf(v2, v3)),
                          fminf(fminf(v4, v5), fminf(v6, v7)));
    acc = fmaxf(acc, m);
  }
  // Scattered store (stride 8 KB across lanes) — only 2048 total, negligible.
  out[lane * G_DIM + g] = acc;
}

extern "C" void kernel_launch(void* const* d_in, const int* in_sizes, int n_in,
                              void* d_out, int out_size, void* d_ws, size_t ws_size,
                              hipStream_t stream) {
  const float* x = (const float*)d_in[0];
  const int*   I = (const int*)d_in[1];
  float* out = (float*)d_out;
  float* xT  = (float*)d_ws;  // 2048*64*4 = 512 KB scratch

  transpose_kernel<<<G_DIM / 64, 256, 0, stream>>>(x, xT);
  gather_minmax_kernel<<<G_DIM / 4, 256, 0, stream>>>(xT, I, out);
}

// Round 3
// 63.369 us; speedup vs baseline: 1.1261x; 1.1261x over previous
//
#include <hip/hip_runtime.h>

// C[b,g] = softor_s( softand_l( x[b, I[g,s,l]] ) ), gamma=1e-3.
// softand~min, softor~max; composed error <= gamma*ln32 = 3.5e-3 << 1.71e-2
// threshold -> hard max-of-min.
//
// B=64 == wave width. Transpose x to xT[g][b] (one 256 B row per g); then a
// gather of row j is perfectly coalesced. This round: 4 g's per wave
// (16-lane quarters), float4 = 4 b's per lane -> 4x fewer VMEM instrs
// (each moves 1 KB). s split 4-ways across the block's waves; combine via
// 4 KB LDS; store float4 per b (out rows g0..g0+3 contiguous).

#define B_DIM 64
#define G_DIM 2048
#define S_DIM 32
#define L_DIM 8

// x[64][2048] -> xT[2048][64]
__global__ __launch_bounds__(256) void transpose_kernel(
    const float* __restrict__ x, float* __restrict__ xT) {
  __shared__ float t[64][65];
  const int g0 = blockIdx.x * 64;
  const int tg = threadIdx.x & 63;   // g within tile
  const int tb = threadIdx.x >> 6;   // 0..3
#pragma unroll
  for (int r = 0; r < 16; ++r) {
    const int b = tb + r * 4;
    t[tg][b] = x[b * G_DIM + g0 + tg];     // coalesced read
  }
  __syncthreads();
#pragma unroll
  for (int r = 0; r < 16; ++r) {
    const int g = tb + r * 4;
    xT[(g0 + g) * B_DIM + tg] = t[g][tg];  // coalesced 256 B row write
  }
}

__global__ __launch_bounds__(256) void gather_minmax_kernel(
    const float* __restrict__ xT, const int* __restrict__ idx,
    float* __restrict__ out) {
  __shared__ float sm[4][4][B_DIM];  // [wave][q][b]

  const int tid  = threadIdx.x;
  const int wave = tid >> 6;         // s-slice: s in [wave*8, wave*8+8)
  const int lane = tid & 63;
  const int q    = lane >> 4;        // g = g0 + q
  const int l16  = lane & 15;        // b-quad: b = 4*l16 .. 4*l16+3
  const int g0   = blockIdx.x * 4;
  const int g    = g0 + q;

  const float4* __restrict__ xv = (const float4*)xT;  // row j = 16 float4
  const int* __restrict__ ip = idx + (g * S_DIM + wave * 8) * L_DIM;

  float4 acc = make_float4(-1e30f, -1e30f, -1e30f, -1e30f);
#pragma unroll
  for (int s = 0; s < 8; ++s) {
    const int4 i0 = ((const int4*)(ip + s * 8))[0];
    const int4 i1 = ((const int4*)(ip + s * 8))[1];
    const float4 a = xv[i0.x * 16 + l16];
    const float4 b = xv[i0.y * 16 + l16];
    const float4 c = xv[i0.z * 16 + l16];
    const float4 d = xv[i0.w * 16 + l16];
    const float4 e = xv[i1.x * 16 + l16];
    const float4 f = xv[i1.y * 16 + l16];
    const float4 h = xv[i1.z * 16 + l16];
    const float4 k = xv[i1.w * 16 + l16];
    float4 m;
    m.x = fminf(fminf(fminf(a.x, b.x), fminf(c.x, d.x)),
                fminf(fminf(e.x, f.x), fminf(h.x, k.x)));
    m.y = fminf(fminf(fminf(a.y, b.y), fminf(c.y, d.y)),
                fminf(fminf(e.y, f.y), fminf(h.y, k.y)));
    m.z = fminf(fminf(fminf(a.z, b.z), fminf(c.z, d.z)),
                fminf(fminf(e.z, f.z), fminf(h.z, k.z)));
    m.w = fminf(fminf(fminf(a.w, b.w), fminf(c.w, d.w)),
                fminf(fminf(e.w, f.w), fminf(h.w, k.w)));
    acc.x = fmaxf(acc.x, m.x);
    acc.y = fmaxf(acc.y, m.y);
    acc.z = fmaxf(acc.z, m.z);
    acc.w = fmaxf(acc.w, m.w);
  }

  ((float4*)sm[wave][q])[l16] = acc;
  __syncthreads();

  if (tid < B_DIM) {
    const int b = tid;
    float4 r;
#pragma unroll
    for (int qq = 0; qq < 4; ++qq) {
      float v = fmaxf(fmaxf(sm[0][qq][b], sm[1][qq][b]),
                      fmaxf(sm[2][qq][b], sm[3][qq][b]));
      (&r.x)[qq] = v;  // component qq -> g0+qq
    }
    *(float4*)(out + (size_t)b * G_DIM + g0) = r;  // g0 % 4 == 0 -> aligned
  }
}

extern "C" void kernel_launch(void* const* d_in, const int* in_sizes, int n_in,
                              void* d_out, int out_size, void* d_ws, size_t ws_size,
                              hipStream_t stream) {
  const float* x = (const float*)d_in[0];
  const int*   I = (const int*)d_in[1];
  float* out = (float*)d_out;
  float* xT  = (float*)d_ws;  // 512 KB scratch

  transpose_kernel<<<G_DIM / 64, 256, 0, stream>>>(x, xT);
  gather_minmax_kernel<<<G_DIM / 4, 256, 0, stream>>>(xT, I, out);
}